// Round 1
// baseline (465.847 us; speedup 1.0000x reference)
//
#include <hip/hip_runtime.h>

#define EPS 1.1920928955078125e-07f

// 12 per-batch statistics (raw sums; zero-meaning folded in at finalize):
// [0] sum p0   [1] sum p1   [2] sum t0   [3] sum t1
// [4] sum p0^2 [5] sum p1^2 [6] sum t0^2 [7] sum t1^2
// [8] sum p0*t0 [9] sum p0*t1 [10] sum p1*t0 [11] sum p1*t1

__global__ __launch_bounds__(256) void pit_partials(
    const float* __restrict__ preds, const float* __restrict__ targets,
    float* __restrict__ ws, int T, int chunks_per_b)
{
    const int b = blockIdx.x / chunks_per_b;
    const int c = blockIdx.x % chunks_per_b;
    const int T4 = T >> 2;                 // float4 count per signal
    const int chunk = T4 / chunks_per_b;   // float4 per chunk (exact: 64000/125=512)

    const float4* p0 = (const float4*)(preds   + (size_t)(b * 2 + 0) * T);
    const float4* p1 = (const float4*)(preds   + (size_t)(b * 2 + 1) * T);
    const float4* t0 = (const float4*)(targets + (size_t)(b * 2 + 0) * T);
    const float4* t1 = (const float4*)(targets + (size_t)(b * 2 + 1) * T);

    float acc[12];
#pragma unroll
    for (int k = 0; k < 12; ++k) acc[k] = 0.f;

    const int beg = c * chunk;
    const int end = beg + chunk;
    for (int i = beg + (int)threadIdx.x; i < end; i += 256) {
        float4 a0 = p0[i];
        float4 a1 = p1[i];
        float4 b0 = t0[i];
        float4 b1 = t1[i];
#pragma unroll
        for (int e = 0; e < 4; ++e) {
            float u0 = (&a0.x)[e], u1 = (&a1.x)[e];
            float v0 = (&b0.x)[e], v1 = (&b1.x)[e];
            acc[0] += u0;       acc[1] += u1;
            acc[2] += v0;       acc[3] += v1;
            acc[4] += u0 * u0;  acc[5] += u1 * u1;
            acc[6] += v0 * v0;  acc[7] += v1 * v1;
            acc[8] += u0 * v0;  acc[9]  += u0 * v1;
            acc[10] += u1 * v0; acc[11] += u1 * v1;
        }
    }

    const int lane = threadIdx.x & 63;
    float* wsb = ws + (size_t)b * 12;
#pragma unroll
    for (int k = 0; k < 12; ++k) {
        float v = acc[k];
        // wave(64)-wide sum
        for (int off = 32; off > 0; off >>= 1) v += __shfl_down(v, off);
        if (lane == 0) atomicAdd(&wsb[k], v);
    }
}

__global__ __launch_bounds__(64) void pit_final(
    const float* __restrict__ ws, float* __restrict__ out, int B, int T)
{
    const int b = threadIdx.x;
    float best = 0.f;
    if (b < B) {
        const float* w = ws + (size_t)b * 12;
        const float invT = 1.0f / (float)T;
        // zero-mean-corrected second moments
        float pp0 = w[4] - w[0] * w[0] * invT;
        float pp1 = w[5] - w[1] * w[1] * invT;
        float tt0 = w[6] - w[2] * w[2] * invT;
        float tt1 = w[7] - w[3] * w[3] * invT;
        float d00 = w[8]  - w[0] * w[2] * invT;
        float d01 = w[9]  - w[0] * w[3] * invT;
        float d10 = w[10] - w[1] * w[2] * invT;
        float d11 = w[11] - w[1] * w[3] * invT;

        auto sisnr = [](float dot, float pp, float tt) -> float {
            float alpha = dot / (tt + EPS);
            float st    = alpha * alpha * tt;
            float noise = pp - 2.0f * alpha * dot + st;
            return 10.0f * log10f((st + EPS) / (noise + EPS));
        };
        float s00 = sisnr(d00, pp0, tt0);
        float s01 = sisnr(d01, pp0, tt1);
        float s10 = sisnr(d10, pp1, tt0);
        float s11 = sisnr(d11, pp1, tt1);

        float perm0 = 0.5f * (s00 + s11);   // identity permutation
        float perm1 = 0.5f * (s01 + s10);   // swapped permutation
        best = fmaxf(perm0, perm1);
    }
    // sum over the single 64-lane wave (lanes >= B contribute 0)
    for (int off = 32; off > 0; off >>= 1) best += __shfl_down(best, off);
    if (threadIdx.x == 0) out[0] = -best / (float)B;
}

extern "C" void kernel_launch(void* const* d_in, const int* in_sizes, int n_in,
                              void* d_out, int out_size, void* d_ws, size_t ws_size,
                              hipStream_t stream)
{
    const float* preds   = (const float*)d_in[0];
    const float* targets = (const float*)d_in[1];
    float* out = (float*)d_out;
    float* ws  = (float*)d_ws;

    const int B = 32;
    const int T = 256000;
    const int chunks_per_b = 125;   // 64000 float4 per signal / 125 = 512 float4 per chunk

    // workspace holds B*12 fp32 accumulators; harness poisons it -> zero first
    hipMemsetAsync(ws, 0, (size_t)B * 12 * sizeof(float), stream);

    pit_partials<<<dim3(B * chunks_per_b), dim3(256), 0, stream>>>(preds, targets, ws, T, chunks_per_b);
    pit_final<<<dim3(1), dim3(64), 0, stream>>>(ws, out, B, T);
}

// Round 2
// 148.472 us; speedup vs baseline: 3.1376x; 3.1376x over previous
//
#include <hip/hip_runtime.h>

#define EPS 1.1920928955078125e-07f

// 12 per-batch statistics (raw sums; zero-meaning folded in at finalize):
// [0] sum p0   [1] sum p1   [2] sum t0   [3] sum t1
// [4] sum p0^2 [5] sum p1^2 [6] sum t0^2 [7] sum t1^2
// [8] sum p0*t0 [9] sum p0*t1 [10] sum p1*t0 [11] sum p1*t1

__global__ __launch_bounds__(256) void pit_partials(
    const float* __restrict__ preds, const float* __restrict__ targets,
    float* __restrict__ ws, int T, int chunks_per_b)
{
    const int b = blockIdx.x / chunks_per_b;
    const int c = blockIdx.x % chunks_per_b;
    const int T4 = T >> 2;                 // float4 count per signal (64000)
    const int chunk = T4 / chunks_per_b;   // 64000/25 = 2560 float4 per block

    const float4* p0 = (const float4*)(preds   + (size_t)(b * 2 + 0) * T);
    const float4* p1 = (const float4*)(preds   + (size_t)(b * 2 + 1) * T);
    const float4* t0 = (const float4*)(targets + (size_t)(b * 2 + 0) * T);
    const float4* t1 = (const float4*)(targets + (size_t)(b * 2 + 1) * T);

    float acc[12];
#pragma unroll
    for (int k = 0; k < 12; ++k) acc[k] = 0.f;

    const int beg = c * chunk;
    const int end = beg + chunk;
    // 10 iterations/thread: enough load-stream depth to hide HBM latency
    for (int i = beg + (int)threadIdx.x; i < end; i += 256) {
        float4 a0 = p0[i];
        float4 a1 = p1[i];
        float4 b0 = t0[i];
        float4 b1 = t1[i];
#pragma unroll
        for (int e = 0; e < 4; ++e) {
            float u0 = (&a0.x)[e], u1 = (&a1.x)[e];
            float v0 = (&b0.x)[e], v1 = (&b1.x)[e];
            acc[0]  += u0;       acc[1]  += u1;
            acc[2]  += v0;       acc[3]  += v1;
            acc[4]  += u0 * u0;  acc[5]  += u1 * u1;
            acc[6]  += v0 * v0;  acc[7]  += v1 * v1;
            acc[8]  += u0 * v0;  acc[9]  += u0 * v1;
            acc[10] += u1 * v0;  acc[11] += u1 * v1;
        }
    }

    // wave(64)-level shuffle reduction for all 12 stats
    const int lane = threadIdx.x & 63;
    const int wave = threadIdx.x >> 6;
#pragma unroll
    for (int k = 0; k < 12; ++k) {
        float v = acc[k];
        for (int off = 32; off > 0; off >>= 1) v += __shfl_down(v, off);
        acc[k] = v;   // valid in lane 0 of each wave
    }

    // block-level reduction through LDS: 4 waves x 12 stats
    __shared__ float lds[4][12];
    if (lane == 0) {
#pragma unroll
        for (int k = 0; k < 12; ++k) lds[wave][k] = acc[k];
    }
    __syncthreads();

    // threads 0..11 each own one stat: sum 4 wave-partials, one atomic per stat
    if (threadIdx.x < 12) {
        float v = lds[0][threadIdx.x] + lds[1][threadIdx.x]
                + lds[2][threadIdx.x] + lds[3][threadIdx.x];
        atomicAdd(&ws[(size_t)b * 12 + threadIdx.x], v);
    }
}

__global__ __launch_bounds__(64) void pit_final(
    const float* __restrict__ ws, float* __restrict__ out, int B, int T)
{
    const int b = threadIdx.x;
    float best = 0.f;
    if (b < B) {
        const float* w = ws + (size_t)b * 12;
        const float invT = 1.0f / (float)T;
        // zero-mean-corrected second moments
        float pp0 = w[4] - w[0] * w[0] * invT;
        float pp1 = w[5] - w[1] * w[1] * invT;
        float tt0 = w[6] - w[2] * w[2] * invT;
        float tt1 = w[7] - w[3] * w[3] * invT;
        float d00 = w[8]  - w[0] * w[2] * invT;
        float d01 = w[9]  - w[0] * w[3] * invT;
        float d10 = w[10] - w[1] * w[2] * invT;
        float d11 = w[11] - w[1] * w[3] * invT;

        auto sisnr = [](float dot, float pp, float tt) -> float {
            float alpha = dot / (tt + EPS);
            float st    = alpha * alpha * tt;
            float noise = pp - 2.0f * alpha * dot + st;
            return 10.0f * log10f((st + EPS) / (noise + EPS));
        };
        float s00 = sisnr(d00, pp0, tt0);
        float s01 = sisnr(d01, pp0, tt1);
        float s10 = sisnr(d10, pp1, tt0);
        float s11 = sisnr(d11, pp1, tt1);

        float perm0 = 0.5f * (s00 + s11);   // identity permutation
        float perm1 = 0.5f * (s01 + s10);   // swapped permutation
        best = fmaxf(perm0, perm1);
    }
    // sum over the single 64-lane wave (lanes >= B contribute 0)
    for (int off = 32; off > 0; off >>= 1) best += __shfl_down(best, off);
    if (threadIdx.x == 0) out[0] = -best / (float)B;
}

extern "C" void kernel_launch(void* const* d_in, const int* in_sizes, int n_in,
                              void* d_out, int out_size, void* d_ws, size_t ws_size,
                              hipStream_t stream)
{
    const float* preds   = (const float*)d_in[0];
    const float* targets = (const float*)d_in[1];
    float* out = (float*)d_out;
    float* ws  = (float*)d_ws;

    const int B = 32;
    const int T = 256000;
    const int chunks_per_b = 25;   // 64000 float4 / 25 = 2560 float4 per block, 10 iter/thread

    // workspace holds B*12 fp32 accumulators; harness poisons it -> zero first
    hipMemsetAsync(ws, 0, (size_t)B * 12 * sizeof(float), stream);

    pit_partials<<<dim3(B * chunks_per_b), dim3(256), 0, stream>>>(preds, targets, ws, T, chunks_per_b);
    pit_final<<<dim3(1), dim3(64), 0, stream>>>(ws, out, B, T);
}

// Round 3
// 146.831 us; speedup vs baseline: 3.1727x; 1.0112x over previous
//
#include <hip/hip_runtime.h>

#define EPS 1.1920928955078125e-07f

// Problem constants (hard-coded so loops fully unroll)
#define BB 32
#define TT 256000
#define CHUNKS 50                 // chunks per batch element
#define T4 (TT / 4)               // 64000 float4 per signal
#define CHUNK (T4 / CHUNKS)       // 1280 float4 per block
#define ITERS (CHUNK / 256)       // 5 iterations per thread
#define NBLK (BB * CHUNKS)        // 1600 partial blocks

// 12 per-batch statistics (raw sums; zero-meaning folded in at finalize):
// [0] sum p0   [1] sum p1   [2] sum t0   [3] sum t1
// [4] sum p0^2 [5] sum p1^2 [6] sum t0^2 [7] sum t1^2
// [8] sum p0*t0 [9] sum p0*t1 [10] sum p1*t0 [11] sum p1*t1

__global__ __launch_bounds__(256, 4) void pit_partials(
    const float* __restrict__ preds, const float* __restrict__ targets,
    float* __restrict__ ws)
{
    const int b = blockIdx.x / CHUNKS;
    const int c = blockIdx.x % CHUNKS;

    const float4* p0 = (const float4*)(preds   + (size_t)(b * 2 + 0) * TT);
    const float4* p1 = (const float4*)(preds   + (size_t)(b * 2 + 1) * TT);
    const float4* t0 = (const float4*)(targets + (size_t)(b * 2 + 0) * TT);
    const float4* t1 = (const float4*)(targets + (size_t)(b * 2 + 1) * TT);

    float acc[12];
#pragma unroll
    for (int k = 0; k < 12; ++k) acc[k] = 0.f;

    const int base = c * CHUNK + (int)threadIdx.x;
#pragma unroll
    for (int it = 0; it < ITERS; ++it) {
        const int i = base + it * 256;
        float4 a0 = p0[i];
        float4 a1 = p1[i];
        float4 b0 = t0[i];
        float4 b1 = t1[i];
#pragma unroll
        for (int e = 0; e < 4; ++e) {
            float u0 = (&a0.x)[e], u1 = (&a1.x)[e];
            float v0 = (&b0.x)[e], v1 = (&b1.x)[e];
            acc[0]  += u0;       acc[1]  += u1;
            acc[2]  += v0;       acc[3]  += v1;
            acc[4]  += u0 * u0;  acc[5]  += u1 * u1;
            acc[6]  += v0 * v0;  acc[7]  += v1 * v1;
            acc[8]  += u0 * v0;  acc[9]  += u0 * v1;
            acc[10] += u1 * v0;  acc[11] += u1 * v1;
        }
    }

    // wave(64)-level shuffle reduction for all 12 stats
    const int lane = threadIdx.x & 63;
    const int wave = threadIdx.x >> 6;
#pragma unroll
    for (int k = 0; k < 12; ++k) {
        float v = acc[k];
        for (int off = 32; off > 0; off >>= 1) v += __shfl_down(v, off);
        acc[k] = v;   // valid in lane 0 of each wave
    }

    __shared__ float lds[4][12];
    if (lane == 0) {
#pragma unroll
        for (int k = 0; k < 12; ++k) lds[wave][k] = acc[k];
    }
    __syncthreads();

    // threads 0..11: sum the 4 wave-partials, plain store (no atomics, no memset needed)
    if (threadIdx.x < 12) {
        float v = lds[0][threadIdx.x] + lds[1][threadIdx.x]
                + lds[2][threadIdx.x] + lds[3][threadIdx.x];
        ws[(size_t)blockIdx.x * 12 + threadIdx.x] = v;
    }
}

// Reduce NBLK x 12 partials -> B x 12 stats -> SI-SNR -> PIT -> scalar loss
__global__ __launch_bounds__(256) void pit_final(
    const float* __restrict__ ws, float* __restrict__ out)
{
    __shared__ float sums[BB * 12];   // 384 stat slots
    __shared__ float bests[BB];

    // each thread owns 1-2 (b,k) stat slots; sums 50 chunk-partials each
    for (int s = threadIdx.x; s < BB * 12; s += 256) {
        const int b = s / 12;
        const int k = s % 12;
        float v = 0.f;
        const float* base = ws + (size_t)(b * CHUNKS) * 12 + k;
#pragma unroll 10
        for (int c = 0; c < CHUNKS; ++c) v += base[(size_t)c * 12];
        sums[s] = v;
    }
    __syncthreads();

    if (threadIdx.x < BB) {
        const float* w = sums + threadIdx.x * 12;
        const float invT = 1.0f / (float)TT;
        float pp0 = w[4] - w[0] * w[0] * invT;
        float pp1 = w[5] - w[1] * w[1] * invT;
        float tt0 = w[6] - w[2] * w[2] * invT;
        float tt1 = w[7] - w[3] * w[3] * invT;
        float d00 = w[8]  - w[0] * w[2] * invT;
        float d01 = w[9]  - w[0] * w[3] * invT;
        float d10 = w[10] - w[1] * w[2] * invT;
        float d11 = w[11] - w[1] * w[3] * invT;

        auto sisnr = [](float dot, float pp, float tt) -> float {
            float alpha = dot / (tt + EPS);
            float st    = alpha * alpha * tt;
            float noise = pp - 2.0f * alpha * dot + st;
            return 10.0f * log10f((st + EPS) / (noise + EPS));
        };
        float s00 = sisnr(d00, pp0, tt0);
        float s01 = sisnr(d01, pp0, tt1);
        float s10 = sisnr(d10, pp1, tt0);
        float s11 = sisnr(d11, pp1, tt1);

        float perm0 = 0.5f * (s00 + s11);   // identity permutation
        float perm1 = 0.5f * (s01 + s10);   // swapped permutation
        bests[threadIdx.x] = fmaxf(perm0, perm1);
    }
    __syncthreads();

    if (threadIdx.x == 0) {
        float acc = 0.f;
#pragma unroll
        for (int b = 0; b < BB; ++b) acc += bests[b];
        out[0] = -acc / (float)BB;
    }
}

extern "C" void kernel_launch(void* const* d_in, const int* in_sizes, int n_in,
                              void* d_out, int out_size, void* d_ws, size_t ws_size,
                              hipStream_t stream)
{
    const float* preds   = (const float*)d_in[0];
    const float* targets = (const float*)d_in[1];
    float* out = (float*)d_out;
    float* ws  = (float*)d_ws;   // NBLK*12 floats = 76.8 KB of scratch

    pit_partials<<<dim3(NBLK), dim3(256), 0, stream>>>(preds, targets, ws);
    pit_final<<<dim3(1), dim3(256), 0, stream>>>(ws, out);
}